// Round 1
// baseline (4419.489 us; speedup 1.0000x reference)
//
#include <hip/hip_runtime.h>
#include <hip/hip_bf16.h>
#include <float.h>

// Problem constants (from reference): B=4, S=2048, D=1024, C=16384, k=8
#define R_TOTAL 8192
#define D_DIM   1024
#define C_TOTAL 16384
#define KSEL    8

#define BM 128      // rows per block tile
#define BN 128      // codes per chunk
#define BK 32       // k-tile
#define ROW_TILES (R_TOTAL / BM)   // 64

// ---------------------------------------------------------------------------
// Kernel 1: c2[c] = sum_d codebook[c][d]^2   (one wave per code)
// ---------------------------------------------------------------------------
__global__ void c2_kernel(const float* __restrict__ cb, float* __restrict__ c2) {
  const int wave = threadIdx.x >> 6;
  const int lane = threadIdx.x & 63;
  const int code = blockIdx.x * 4 + wave;
  const float* row = cb + (size_t)code * D_DIM;
  float s = 0.f;
  #pragma unroll
  for (int i = 0; i < D_DIM / 64; ++i) { float v = row[lane + i * 64]; s += v * v; }
  #pragma unroll
  for (int off = 32; off >= 1; off >>= 1) s += __shfl_xor(s, off, 64);
  if (lane == 0) c2[code] = s;
}

// ---------------------------------------------------------------------------
// Kernel 2: tiled f32 GEMM (scores = 2*X.CB^T - c2) with fused per-row top-8.
// Grid: ROW_TILES * nsplit blocks; block handles BM rows x (C/nsplit) codes.
// Partial top-8 (value,id) per (row, segment) written to workspace.
// ---------------------------------------------------------------------------
__global__ __launch_bounds__(256, 2)
void dist_topk_kernel(const float* __restrict__ X, const float* __restrict__ CB,
                      const float* __restrict__ c2g,
                      float* __restrict__ pval, int* __restrict__ pid,
                      int nsplit) {
  // A_s/B_s: [128][36] f32 each (pad 4 keeps rows 16B-aligned, breaks pow2 stride)
  // S_s: scores [128][65] f32, overlaps A_s/B_s (sequenced by barriers)
  __shared__ float smem[2 * 128 * 36];
  float* A_s = smem;
  float* B_s = smem + 128 * 36;
  float* S_s = smem;

  const int t  = threadIdx.x;
  const int tx = t & 15;   // code group: codes tx + 16j
  const int ty = t >> 4;   // row group:  rows  ty + 16i

  const int seg     = blockIdx.x / ROW_TILES;  // consecutive blocks share a segment
  const int rowTile = blockIdx.x % ROW_TILES;
  const int cseg    = C_TOTAL / nsplit;
  const int nchunk  = cseg / BN;
  const int rb      = rowTile * BM;
  const int cb0     = seg * cseg;

  float topv[KSEL]; int topi[KSEL];
  #pragma unroll
  for (int q = 0; q < KSEL; ++q) { topv[q] = -FLT_MAX; topi[q] = 0; }

  for (int ch = 0; ch < nchunk; ++ch) {
    const int cbase = cb0 + ch * BN;

    float acc[8][8];
    #pragma unroll
    for (int i = 0; i < 8; ++i)
      #pragma unroll
      for (int j = 0; j < 8; ++j) acc[i][j] = 0.f;

    for (int kt = 0; kt < D_DIM; kt += BK) {
      __syncthreads();   // previous consumers (scan / k-loop) done before overwrite
      {
        const int r4 = t >> 3;
        const int c4 = (t & 7) * 4;
        #pragma unroll
        for (int p = 0; p < 4; ++p) {
          const int row = p * 32 + r4;
          float4 va = *(const float4*)(X  + (size_t)(rb    + row) * D_DIM + kt + c4);
          *(float4*)&A_s[row * 36 + c4] = va;
          float4 vb = *(const float4*)(CB + (size_t)(cbase + row) * D_DIM + kt + c4);
          *(float4*)&B_s[row * 36 + c4] = vb;
        }
      }
      __syncthreads();
      #pragma unroll
      for (int k4 = 0; k4 < BK / 4; ++k4) {
        float4 a[8], b[8];
        #pragma unroll
        for (int i = 0; i < 8; ++i) a[i] = *(const float4*)&A_s[(ty + i * 16) * 36 + k4 * 4];
        #pragma unroll
        for (int j = 0; j < 8; ++j) b[j] = *(const float4*)&B_s[(tx + j * 16) * 36 + k4 * 4];
        #pragma unroll
        for (int i = 0; i < 8; ++i)
          #pragma unroll
          for (int j = 0; j < 8; ++j) {
            acc[i][j] += a[i].x * b[j].x;
            acc[i][j] += a[i].y * b[j].y;
            acc[i][j] += a[i].z * b[j].z;
            acc[i][j] += a[i].w * b[j].w;
          }
      }
    }

    // scores: s = 2*xc - c2  (x2 is row-constant, irrelevant for ranking)
    float myc2[8];
    #pragma unroll
    for (int j = 0; j < 8; ++j) myc2[j] = c2g[cbase + tx + j * 16];

    #pragma unroll
    for (int half = 0; half < 2; ++half) {
      __syncthreads();
      #pragma unroll
      for (int jj = 0; jj < 4; ++jj) {
        const int j   = half * 4 + jj;
        const int col = tx + jj * 16;          // local col in [0,64)
        #pragma unroll
        for (int i = 0; i < 8; ++i)
          S_s[(ty + i * 16) * 65 + col] = 2.f * acc[i][j] - myc2[j];
      }
      __syncthreads();
      if (t < BM) {  // one thread per row scans 64 scores, ascending code id
        const int cidbase = cbase + half * 64;
        #pragma unroll 4
        for (int c = 0; c < 64; ++c) {
          const float s = S_s[t * 65 + c];
          if (s > topv[KSEL - 1]) {           // strict > keeps lower-id-first ties
            float cv = s; int ci = cidbase + c;
            #pragma unroll
            for (int q = 0; q < KSEL; ++q) {
              if (cv > topv[q]) {
                const float tv = topv[q]; const int ti = topi[q];
                topv[q] = cv; topi[q] = ci;
                cv = tv; ci = ti;
              }
            }
          }
        }
      }
    }
  }

  if (t < BM) {
    const int row = rb + t;
    const size_t base = ((size_t)row * nsplit + seg) * KSEL;
    #pragma unroll
    for (int q = 0; q < KSEL; ++q) { pval[base + q] = topv[q]; pid[base + q] = topi[q]; }
  }
}

// ---------------------------------------------------------------------------
// Kernel 3: merge per-segment top-8 partials -> final sorted top-8 ids,
// then gather codebook rows and average. One block per row.
// ---------------------------------------------------------------------------
__global__ void merge_gather_kernel(const float* __restrict__ CB,
                                    const float* __restrict__ pval,
                                    const int* __restrict__ pid,
                                    float* __restrict__ out,
                                    float* __restrict__ out_ids,
                                    int nsplit) {
  const int row = blockIdx.x;
  const int t = threadIdx.x;
  __shared__ int sids[KSEL];

  if (t == 0) {
    const int ncand = nsplit * KSEL;   // <= 64
    const float* pv = pval + (size_t)row * ncand;
    const int*   pi = pid  + (size_t)row * ncand;
    unsigned long long used = 0ull;
    for (int q = 0; q < KSEL; ++q) {
      float best = -FLT_MAX; int bid = 0x7fffffff; int bpos = 0;
      for (int c = 0; c < ncand; ++c) {
        if ((used >> c) & 1ull) continue;
        const float v = pv[c]; const int cid = pi[c];
        if (v > best || (v == best && cid < bid)) { best = v; bid = cid; bpos = c; }
      }
      used |= 1ull << bpos;
      sids[q] = bid;
      out_ids[(size_t)row * KSEL + q] = (float)bid;  // ids as float in f32 out buffer
    }
  }
  __syncthreads();

  #pragma unroll
  for (int rep = 0; rep < D_DIM / 256; ++rep) {
    const int d = rep * 256 + t;
    float s = 0.f;
    #pragma unroll
    for (int q = 0; q < KSEL; ++q) s += CB[(size_t)sids[q] * D_DIM + d];
    out[(size_t)row * D_DIM + d] = s * 0.125f;   // / kcodes (=8)
  }
}

// ---------------------------------------------------------------------------
extern "C" void kernel_launch(void* const* d_in, const int* in_sizes, int n_in,
                              void* d_out, int out_size, void* d_ws, size_t ws_size,
                              hipStream_t stream) {
  const float* X  = (const float*)d_in[0];
  const float* CB = (const float*)d_in[1];
  // d_in[2] = kcodes (device scalar); reference fixes it at 8 -> compiled in.

  float* out     = (float*)d_out;
  float* out_ids = out + (size_t)R_TOTAL * D_DIM;

  // workspace: c2 (64KB) | pval (R*nsplit*8 f32) | pid (R*nsplit*8 i32)
  int nsplit = 8;
  while (nsplit > 1 &&
         ws_size < (size_t)C_TOTAL * 4 + (size_t)R_TOTAL * nsplit * KSEL * 8) {
    nsplit >>= 1;
  }
  float* c2   = (float*)d_ws;
  float* pval = (float*)((char*)d_ws + (size_t)C_TOTAL * 4);
  int*   pid  = (int*)(pval + (size_t)R_TOTAL * nsplit * KSEL);

  hipLaunchKernelGGL(c2_kernel, dim3(C_TOTAL / 4), dim3(256), 0, stream, CB, c2);
  hipLaunchKernelGGL(dist_topk_kernel, dim3(ROW_TILES * nsplit), dim3(256), 0, stream,
                     X, CB, c2, pval, pid, nsplit);
  hipLaunchKernelGGL(merge_gather_kernel, dim3(R_TOTAL), dim3(256), 0, stream,
                     CB, pval, pid, out, out_ids, nsplit);
}

// Round 2
// 1133.352 us; speedup vs baseline: 3.8995x; 3.8995x over previous
//
#include <hip/hip_runtime.h>
#include <hip/hip_bf16.h>
#include <float.h>

// Problem constants: B=4, S=2048, D=1024, C=16384, k=8
#define R_TOTAL 8192
#define D_DIM   1024
#define C_TOTAL 16384
#define KSEL    8
#define XN  ((size_t)R_TOTAL * D_DIM)   // 8,388,608
#define CBN ((size_t)C_TOTAL * D_DIM)   // 16,777,216

typedef __attribute__((ext_vector_type(8))) short short8v;   // 8 x bf16 (4 VGPR)
typedef __attribute__((ext_vector_type(4))) float f32x4;
typedef __attribute__((ext_vector_type(8))) unsigned short ushort8;

__device__ __forceinline__ unsigned short f2bf(float f) {  // RNE f32->bf16
  unsigned u = __float_as_uint(f);
  u = (u + 0x7fffu + ((u >> 16) & 1u)) >> 16;
  return (unsigned short)u;
}

__device__ __forceinline__ void gload_lds16(const void* g, void* l) {
  __builtin_amdgcn_global_load_lds((const __attribute__((address_space(1))) void*)g,
                                   (__attribute__((address_space(3))) void*)l, 16, 0, 0);
}

// ---------------------------------------------------------------------------
// Kernel 0: f32 -> bf16 conversion of X and CB (memory-bound, ~145MB)
// ---------------------------------------------------------------------------
__global__ void cvt_kernel(const float* __restrict__ X, const float* __restrict__ CB,
                           unsigned short* __restrict__ Xb, unsigned short* __restrict__ CBb) {
  size_t e = ((size_t)blockIdx.x * 256 + threadIdx.x) * 8;
  const float* src; unsigned short* dst; size_t off;
  if (e < XN) { src = X;  dst = Xb;  off = e; }
  else        { src = CB; dst = CBb; off = e - XN; }
  float4 v0 = *(const float4*)(src + off);
  float4 v1 = *(const float4*)(src + off + 4);
  ushort8 o;
  o[0]=f2bf(v0.x); o[1]=f2bf(v0.y); o[2]=f2bf(v0.z); o[3]=f2bf(v0.w);
  o[4]=f2bf(v1.x); o[5]=f2bf(v1.y); o[6]=f2bf(v1.z); o[7]=f2bf(v1.w);
  *(ushort8*)(dst + off) = o;
}

// ---------------------------------------------------------------------------
// Kernel 1: c2[c] = sum_d CB[c][d]^2 (f32, one wave per code)
// ---------------------------------------------------------------------------
__global__ void c2_kernel(const float* __restrict__ cb, float* __restrict__ c2) {
  const int wave = threadIdx.x >> 6;
  const int lane = threadIdx.x & 63;
  const int code = blockIdx.x * 4 + wave;
  const float* row = cb + (size_t)code * D_DIM;
  float s = 0.f;
  #pragma unroll
  for (int i = 0; i < D_DIM / 64; ++i) { float v = row[lane + i * 64]; s += v * v; }
  #pragma unroll
  for (int off = 32; off >= 1; off >>= 1) s += __shfl_xor(s, off, 64);
  if (lane == 0) c2[code] = s;
}

// ---------------------------------------------------------------------------
// Kernel 2: bf16 MFMA GEMM computing S^T tiles (codes x xrows) with fused
// per-xrow approximate top-8 per code-segment.
// Block: 256 thr (4 waves). Tile: 128 codes x 128 xrows, BK=64.
// Wave w covers all 128 codes x xrows [w*32, w*32+32): frags 8(fm) x 2(fn).
// MFMA 16x16x32_bf16: A lane row=l&15,k=(l>>4)*8+j; B lane col=l&15 (xrow);
// C/D: col(xrow)=l&15, row(code)=(l>>4)*4+r  [m89-verified layout].
// LDS tiles row-major [128][64] bf16 with XOR swizzle byte^=((row&7)<<4),
// applied on the *global source* (linear global_load_lds dest) + on reads.
// ---------------------------------------------------------------------------
__global__ __launch_bounds__(256)
void gemm_topk_kernel(const unsigned short* __restrict__ Xb,
                      const unsigned short* __restrict__ CBb,
                      const float* __restrict__ c2g,
                      int* __restrict__ pid, int nsplit) {
  __shared__ short A_s[128 * 64];   // codes tile, 16KB
  __shared__ short X_s[128 * 64];   // xrow  tile, 16KB

  const int t  = threadIdx.x;
  const int w  = t >> 6;
  const int ln = t & 63;
  const int lx = ln & 15;
  const int lg = ln >> 4;

  const int xt    = blockIdx.x & 63;      // xrow tile (grid = 64 * nsplit)
  const int seg   = blockIdx.x >> 6;
  const int xbase = xt * 128;
  const int cseg  = C_TOTAL / nsplit;
  const int nchunk = cseg / 128;
  const int cb0   = seg * cseg;

  // per-lane running top-8, one list per fn (xrow block)
  float tv[2][KSEL]; int ti[2][KSEL];
  #pragma unroll
  for (int fn = 0; fn < 2; ++fn)
    #pragma unroll
    for (int q = 0; q < KSEL; ++q) { tv[fn][q] = -FLT_MAX; ti[fn][q] = 0; }

  // staging: issue i covers rows [i*32, i*32+32); thread t -> LDS byte i*4096+t*16
  const int srow = t >> 3;                        // row within 32-row group
  const int skel = (((t & 7) * 16) ^ ((srow & 7) << 4)) >> 1;  // swizzled src k-elem
  const int fsw  = (lx & 7) << 4;                 // read-side swizzle

  for (int ch = 0; ch < nchunk; ++ch) {
    const int cbase = cb0 + ch * 128;
    f32x4 acc[8][2];
    #pragma unroll
    for (int fm = 0; fm < 8; ++fm) {
      acc[fm][0] = (f32x4){0.f, 0.f, 0.f, 0.f};
      acc[fm][1] = (f32x4){0.f, 0.f, 0.f, 0.f};
    }

    for (int kt = 0; kt < D_DIM; kt += 64) {
      __syncthreads();   // previous readers done before overwrite
      #pragma unroll
      for (int i = 0; i < 4; ++i) {
        const int row = i * 32 + srow;
        gload_lds16(CBb + (size_t)(cbase + row) * D_DIM + kt + skel,
                    (char*)A_s + i * 4096 + t * 16);
      }
      #pragma unroll
      for (int i = 0; i < 4; ++i) {
        const int row = i * 32 + srow;
        gload_lds16(Xb + (size_t)(xbase + row) * D_DIM + kt + skel,
                    (char*)X_s + i * 4096 + t * 16);
      }
      __syncthreads();   // compiler drains vmcnt before barrier -> LDS ready

      #pragma unroll
      for (int kh = 0; kh < 2; ++kh) {
        const int kbs = kh * 64 + lg * 16;
        short8v b0 = *(const short8v*)((const char*)X_s + (w * 32      + lx) * 128 + (kbs ^ fsw));
        short8v b1 = *(const short8v*)((const char*)X_s + (w * 32 + 16 + lx) * 128 + (kbs ^ fsw));
        #pragma unroll
        for (int fm = 0; fm < 8; ++fm) {
          short8v a = *(const short8v*)((const char*)A_s + (fm * 16 + lx) * 128 + (kbs ^ fsw));
          acc[fm][0] = __builtin_amdgcn_mfma_f32_16x16x32_bf16(a, b0, acc[fm][0], 0, 0, 0);
          acc[fm][1] = __builtin_amdgcn_mfma_f32_16x16x32_bf16(a, b1, acc[fm][1], 0, 0, 0);
        }
      }
    }

    // selection epilogue: scores s = 2*xc - c2; lane holds codes fm*16+lg*4+r
    #pragma unroll
    for (int fm = 0; fm < 8; ++fm) {
      const int cloc = fm * 16 + lg * 4;
      const float4 cc = *(const float4*)(c2g + cbase + cloc);
      #pragma unroll
      for (int fn = 0; fn < 2; ++fn) {
        #pragma unroll
        for (int r = 0; r < 4; ++r) {
          const float ccr = (r == 0) ? cc.x : (r == 1) ? cc.y : (r == 2) ? cc.z : cc.w;
          const float s = 2.f * acc[fm][fn][r] - ccr;
          if (s > tv[fn][KSEL - 1]) {
            float cv = s; int ci = cbase + cloc + r;
            #pragma unroll
            for (int q = 0; q < KSEL; ++q) {
              if (cv > tv[fn][q]) {
                const float t0 = tv[fn][q]; tv[fn][q] = cv; cv = t0;
                const int   t1 = ti[fn][q]; ti[fn][q] = ci; ci = t1;
              }
            }
          }
        }
      }
    }
  }

  // merge the 4 lane-groups per xrow via LDS (reuse tiles: 16KB + 16KB)
  __syncthreads();
  float* mv = (float*)A_s;   // [128 xrows][4 groups][8]
  int*   mi = (int*)X_s;
  #pragma unroll
  for (int fn = 0; fn < 2; ++fn) {
    const int xr = w * 32 + fn * 16 + lx;
    #pragma unroll
    for (int q = 0; q < KSEL; ++q) {
      mv[(xr * 4 + lg) * 8 + q] = tv[fn][q];
      mi[(xr * 4 + lg) * 8 + q] = ti[fn][q];
    }
  }
  __syncthreads();
  if (t < 128) {
    float bv[KSEL]; int bi[KSEL];
    #pragma unroll
    for (int q = 0; q < KSEL; ++q) { bv[q] = -FLT_MAX; bi[q] = 0x7fffffff; }
    for (int c = 0; c < 32; ++c) {
      float cv = mv[t * 32 + c]; int ci = mi[t * 32 + c];
      if (cv > bv[KSEL - 1] || (cv == bv[KSEL - 1] && ci < bi[KSEL - 1])) {
        #pragma unroll
        for (int q = 0; q < KSEL; ++q) {
          if (cv > bv[q] || (cv == bv[q] && ci < bi[q])) {
            const float t0 = bv[q]; bv[q] = cv; cv = t0;
            const int   t1 = bi[q]; bi[q] = ci; ci = t1;
          }
        }
      }
    }
    const size_t base = ((size_t)(xbase + t) * nsplit + seg) * KSEL;
    #pragma unroll
    for (int q = 0; q < KSEL; ++q) pid[base + q] = bi[q];
  }
}

// ---------------------------------------------------------------------------
// Kernel 3: exact f32 rescore of candidates, final top-8 (ties: lower id),
// gather + average. One block per xrow.
// ---------------------------------------------------------------------------
__global__ __launch_bounds__(256)
void rescore_kernel(const float* __restrict__ X, const float* __restrict__ CB,
                    const float* __restrict__ c2g, const int* __restrict__ pid,
                    float* __restrict__ out, float* __restrict__ out_ids, int nsplit) {
  const int row = blockIdx.x;
  const int t = threadIdx.x;
  __shared__ float xs[D_DIM];
  __shared__ float sv[64];
  __shared__ int   sid[64];
  __shared__ int   topid[KSEL];

  *(float4*)&xs[t * 4] = *(const float4*)(X + (size_t)row * D_DIM + t * 4);
  const int ncand = nsplit * KSEL;
  if (t < ncand) sid[t] = pid[(size_t)row * ncand + t];
  __syncthreads();

  const int w = t >> 6, ln = t & 63;
  for (int c = w; c < ncand; c += 4) {
    const int id = sid[c];
    const float* cr = CB + (size_t)id * D_DIM;
    float s = 0.f;
    #pragma unroll
    for (int i = 0; i < 4; ++i) {
      const float4 cv = *(const float4*)(cr + ln * 4 + i * 256);
      const float4 xv = *(const float4*)&xs[ln * 4 + i * 256];
      s += cv.x * xv.x + cv.y * xv.y + cv.z * xv.z + cv.w * xv.w;
    }
    #pragma unroll
    for (int off = 32; off >= 1; off >>= 1) s += __shfl_xor(s, off, 64);
    if (ln == 0) sv[c] = 2.f * s - c2g[id];
  }
  __syncthreads();

  if (t == 0) {
    float bv[KSEL]; int bi[KSEL];
    #pragma unroll
    for (int q = 0; q < KSEL; ++q) { bv[q] = -FLT_MAX; bi[q] = 0x7fffffff; }
    for (int c = 0; c < ncand; ++c) {
      float cv = sv[c]; int ci = sid[c];
      #pragma unroll
      for (int q = 0; q < KSEL; ++q) {
        if (cv > bv[q] || (cv == bv[q] && ci < bi[q])) {
          const float t0 = bv[q]; bv[q] = cv; cv = t0;
          const int   t1 = bi[q]; bi[q] = ci; ci = t1;
        }
      }
    }
    #pragma unroll
    for (int q = 0; q < KSEL; ++q) {
      topid[q] = bi[q];
      out_ids[(size_t)row * KSEL + q] = (float)bi[q];
    }
  }
  __syncthreads();

  float4 a = {0.f, 0.f, 0.f, 0.f};
  #pragma unroll
  for (int q = 0; q < KSEL; ++q) {   // sum in value-desc order, matching ref
    const float4 cv = *(const float4*)(CB + (size_t)topid[q] * D_DIM + t * 4);
    a.x += cv.x; a.y += cv.y; a.z += cv.z; a.w += cv.w;
  }
  a.x *= 0.125f; a.y *= 0.125f; a.z *= 0.125f; a.w *= 0.125f;
  *(float4*)(out + (size_t)row * D_DIM + t * 4) = a;
}

// ---------------------------------------------------------------------------
extern "C" void kernel_launch(void* const* d_in, const int* in_sizes, int n_in,
                              void* d_out, int out_size, void* d_ws, size_t ws_size,
                              hipStream_t stream) {
  const float* X  = (const float*)d_in[0];
  const float* CB = (const float*)d_in[1];
  // d_in[2] = kcodes, fixed at 8 (compiled in)

  float* out     = (float*)d_out;
  float* out_ids = out + XN;

  int nsplit = 8;
  const size_t XbB  = XN * 2;        // 16 MB
  const size_t CBbB = CBN * 2;       // 32 MB (== outputs region of d_out exactly)
  const size_t c2B  = C_TOTAL * 4;   // 64 KB

  char* p = (char*)d_ws;
  unsigned short* Xb;
  unsigned short* CBb;
  if (ws_size >= XbB + CBbB + c2B + (size_t)R_TOTAL * 8 * KSEL * 4) {
    Xb  = (unsigned short*)p; p += XbB;
    CBb = (unsigned short*)p; p += CBbB;
  } else {
    // CB bf16 lives in d_out's outputs region (overwritten by rescore at the end)
    CBb = (unsigned short*)d_out;
    while (nsplit > 1 &&
           ws_size < XbB + c2B + (size_t)R_TOTAL * nsplit * KSEL * 4) nsplit >>= 1;
    Xb = (unsigned short*)p; p += XbB;
  }
  float* c2  = (float*)p; p += c2B;
  int*   pid = (int*)p;

  hipLaunchKernelGGL(cvt_kernel, dim3((unsigned)((XN + CBN) / 8 / 256)), dim3(256), 0, stream,
                     X, CB, Xb, CBb);
  hipLaunchKernelGGL(c2_kernel, dim3(C_TOTAL / 4), dim3(256), 0, stream, CB, c2);
  hipLaunchKernelGGL(gemm_topk_kernel, dim3(64 * nsplit), dim3(256), 0, stream,
                     Xb, CBb, c2, pid, nsplit);
  hipLaunchKernelGGL(rescore_kernel, dim3(R_TOTAL), dim3(256), 0, stream,
                     X, CB, c2, pid, out, out_ids, nsplit);
}

// Round 3
// 602.061 us; speedup vs baseline: 7.3406x; 1.8825x over previous
//
#include <hip/hip_runtime.h>
#include <hip/hip_bf16.h>
#include <float.h>

// Problem constants: B=4, S=2048, D=1024, C=16384, k=8
#define R_TOTAL 8192
#define D_DIM   1024
#define C_TOTAL 16384
#define KSEL    8
#define XN  ((size_t)R_TOTAL * D_DIM)   // 8,388,608
#define CBN ((size_t)C_TOTAL * D_DIM)   // 16,777,216
#define NSPLIT  8
#define SEGC    (C_TOTAL / NSPLIT)      // 2048 codes per segment (per block)
#define NCHUNK  (SEGC / 256)            // 8 chunks of 256 codes
#define NKT     (NCHUNK * 16)           // 128 K-tiles (BK=64) per block
#define NC_RES  24                      // candidates exact-rescored per row

typedef __attribute__((ext_vector_type(8)))  short short8v;   // 8 bf16
typedef __attribute__((ext_vector_type(16))) float f32x16;
typedef __attribute__((ext_vector_type(8)))  unsigned short ushort8;

__device__ __forceinline__ unsigned short f2bf(float f) {  // RNE f32->bf16
  unsigned u = __float_as_uint(f);
  u = (u + 0x7fffu + ((u >> 16) & 1u)) >> 16;
  return (unsigned short)u;
}

__device__ __forceinline__ void gload_lds16(const void* g, void* l) {
  __builtin_amdgcn_global_load_lds((const __attribute__((address_space(1))) void*)g,
                                   (__attribute__((address_space(3))) void*)l, 16, 0, 0);
}

// ---------------------------------------------------------------------------
// Kernel 0: f32 -> bf16 conversion of X and CB
// ---------------------------------------------------------------------------
__global__ void cvt_kernel(const float* __restrict__ X, const float* __restrict__ CB,
                           unsigned short* __restrict__ Xb, unsigned short* __restrict__ CBb) {
  size_t e = ((size_t)blockIdx.x * 256 + threadIdx.x) * 8;
  const float* src; unsigned short* dst; size_t off;
  if (e < XN) { src = X;  dst = Xb;  off = e; }
  else        { src = CB; dst = CBb; off = e - XN; }
  float4 v0 = *(const float4*)(src + off);
  float4 v1 = *(const float4*)(src + off + 4);
  ushort8 o;
  o[0]=f2bf(v0.x); o[1]=f2bf(v0.y); o[2]=f2bf(v0.z); o[3]=f2bf(v0.w);
  o[4]=f2bf(v1.x); o[5]=f2bf(v1.y); o[6]=f2bf(v1.z); o[7]=f2bf(v1.w);
  *(ushort8*)(dst + off) = o;
}

// ---------------------------------------------------------------------------
// Kernel 1: c2[c] = sum_d CB[c][d]^2 (f32 exact, one wave per code)
// ---------------------------------------------------------------------------
__global__ void c2_kernel(const float* __restrict__ cb, float* __restrict__ c2) {
  const int wave = threadIdx.x >> 6;
  const int lane = threadIdx.x & 63;
  const int code = blockIdx.x * 4 + wave;
  const float* row = cb + (size_t)code * D_DIM;
  float s = 0.f;
  #pragma unroll
  for (int i = 0; i < D_DIM / 64; ++i) { float v = row[lane + i * 64]; s += v * v; }
  #pragma unroll
  for (int off = 32; off >= 1; off >>= 1) s += __shfl_xor(s, off, 64);
  if (lane == 0) c2[code] = s;
}

// ---------------------------------------------------------------------------
// Kernel 2: bf16 MFMA GEMM (S^T tiles: 256 codes x 256 xrows) with fused
// per-xrow approximate top-8 per 2048-code segment.
// 512 thr = 8 waves (2M x 4N). Per wave: 128 codes x 64 xrows via
// mfma_f32_32x32x16_bf16 (fm 0..3, fn 0..1, ks 0..3 per BK=64 tile).
// LDS (dynamic 136KB): A slots 2x32KB | X slots 2x32KB | c2 seg 8KB.
// Pipeline: stage K-tile g+1 (8x global_load_lds16/thread) at top of iter g,
// raw s_barrier + s_waitcnt vmcnt(8) keeps next tile's loads in flight
// across this tile's MFMA (no full drain).
// Swizzle: LDS rows [*, 64K] bf16, kbyte ^= ((row&7)<<4), applied on global
// source (linear gload_lds dest) and on ds_read addresses (both-sides).
// ---------------------------------------------------------------------------
__global__ __launch_bounds__(512, 2)
void gemm_topk_kernel(const unsigned short* __restrict__ Xb,
                      const unsigned short* __restrict__ CBb,
                      const float* __restrict__ c2g,
                      float* __restrict__ pval, int* __restrict__ pid) {
  extern __shared__ char smem[];
  // layout: A slot0 @0, A slot1 @32KB, X slot0 @64KB, X slot1 @96KB, c2 @128KB
  float* c2s = (float*)(smem + 131072);

  const int t   = threadIdx.x;
  const int wid = t >> 6, l = t & 63;
  const int wr  = wid >> 2;          // 0..1: code half (128 rows)
  const int wc  = wid & 3;           // 0..3: xrow quarter (64 cols)
  const int l31 = l & 31, hi = l >> 5;

  const int xt    = blockIdx.x & 31;        // 32 xrow tiles
  const int seg   = blockIdx.x >> 5;        // 8 segments
  const int xbase = xt * 256;
  const int cb0   = seg * SEGC;

  // preload segment c2 into LDS (512 thr x float4 = 2048 f32)
  *(float4*)&c2s[t * 4] = *(const float4*)(c2g + cb0 + t * 4);
  asm volatile("s_waitcnt lgkmcnt(0)" ::: "memory");

  // staging constants: issue i covers rows i*64+(t>>3); 16B col chunk (t&7)
  const int srow = t >> 3;
  const int sswz = (((t & 7) * 16) ^ ((srow & 7) << 4)) >> 1;  // elem offset
  const int fswz = (l & 7) << 4;                                // read swizzle

  // accumulators + selection state
  f32x16 acc[4][2];
  float tv[2][KSEL]; int ti[2][KSEL];
  #pragma unroll
  for (int fm = 0; fm < 4; ++fm)
    #pragma unroll
    for (int fn = 0; fn < 2; ++fn)
      #pragma unroll
      for (int r = 0; r < 16; ++r) acc[fm][fn][r] = 0.f;
  #pragma unroll
  for (int fn = 0; fn < 2; ++fn)
    #pragma unroll
    for (int q = 0; q < KSEL; ++q) { tv[fn][q] = -FLT_MAX; ti[fn][q] = 0; }

  // ---- staging helper (issues 8 x 16B loads for K-tile g) ----
  auto STAGE = [&](int g) {
    const int kbase = (g & 15) * 64;
    const int arow0 = cb0 + (g >> 4) * 256;
    char* As = smem + (g & 1) * 32768;
    char* Xs = smem + 65536 + (g & 1) * 32768;
    #pragma unroll
    for (int i = 0; i < 4; ++i)
      gload_lds16(CBb + (size_t)(arow0 + i * 64 + srow) * D_DIM + kbase + sswz,
                  As + (i * 512 + t) * 16);
    #pragma unroll
    for (int i = 0; i < 4; ++i)
      gload_lds16(Xb + (size_t)(xbase + i * 64 + srow) * D_DIM + kbase + sswz,
                  Xs + (i * 512 + t) * 16);
  };

  STAGE(0);

  for (int g = 0; g < NKT; ++g) {
    if (g + 1 < NKT) {
      STAGE(g + 1);
      asm volatile("s_waitcnt vmcnt(8)" ::: "memory");  // K-tile g landed
    } else {
      asm volatile("s_waitcnt vmcnt(0)" ::: "memory");
    }
    __builtin_amdgcn_s_barrier();

    const char* As = smem + (g & 1) * 32768;
    const char* Xs = smem + 65536 + (g & 1) * 32768;

    #pragma unroll
    for (int ks2 = 0; ks2 < 4; ks2 += 2) {
      short8v av[4][2], bv[2][2];
      #pragma unroll
      for (int fm = 0; fm < 4; ++fm)
        #pragma unroll
        for (int j = 0; j < 2; ++j) {
          const int row = wr * 128 + fm * 32 + l31;
          const int kb  = (((ks2 + j) * 32 + hi * 16)) ^ fswz;
          av[fm][j] = *(const short8v*)(As + row * 128 + kb);
        }
      #pragma unroll
      for (int fn = 0; fn < 2; ++fn)
        #pragma unroll
        for (int j = 0; j < 2; ++j) {
          const int row = wc * 64 + fn * 32 + l31;
          const int kb  = (((ks2 + j) * 32 + hi * 16)) ^ fswz;
          bv[fn][j] = *(const short8v*)(Xs + row * 128 + kb);
        }
      __builtin_amdgcn_s_setprio(1);
      #pragma unroll
      for (int fm = 0; fm < 4; ++fm)
        #pragma unroll
        for (int fn = 0; fn < 2; ++fn)
          #pragma unroll
          for (int j = 0; j < 2; ++j)
            acc[fm][fn] = __builtin_amdgcn_mfma_f32_32x32x16_bf16(
                av[fm][j], bv[fn][j], acc[fm][fn], 0, 0, 0);
      __builtin_amdgcn_s_setprio(0);
    }
    __builtin_amdgcn_s_barrier();   // slot reads done before next overwrite

    if ((g & 15) == 15) {
      // -------- selection epilogue for chunk ch --------
      const int ch = g >> 4;
      #pragma unroll
      for (int fm = 0; fm < 4; ++fm) {
        const int rloc = ch * 256 + wr * 128 + fm * 32 + hi * 4;
        const int idb  = cb0 + wr * 128 + ch * 256 + fm * 32 + hi * 4;
        #pragma unroll
        for (int q = 0; q < 4; ++q) {
          const float4 cq = *(const float4*)&c2s[rloc + q * 8];
          #pragma unroll
          for (int fn = 0; fn < 2; ++fn) {
            #pragma unroll
            for (int r = 0; r < 4; ++r) {
              const float c2v = (r == 0) ? cq.x : (r == 1) ? cq.y : (r == 2) ? cq.z : cq.w;
              const float s = 2.f * acc[fm][fn][q * 4 + r] - c2v;
              if (s > tv[fn][KSEL - 1]) {      // strict >: ids scanned ascending
                float cv = s; int ci = idb + q * 8 + r;
                #pragma unroll
                for (int q2 = 0; q2 < KSEL; ++q2) {
                  if (cv > tv[fn][q2]) {
                    const float t0 = tv[fn][q2]; tv[fn][q2] = cv; cv = t0;
                    const int   t1 = ti[fn][q2]; ti[fn][q2] = ci; ci = t1;
                  }
                }
              }
            }
          }
        }
      }
      // reset accumulators for next chunk
      #pragma unroll
      for (int fm = 0; fm < 4; ++fm)
        #pragma unroll
        for (int fn = 0; fn < 2; ++fn)
          #pragma unroll
          for (int r = 0; r < 16; ++r) acc[fm][fn][r] = 0.f;
    }
  }

  // -------- merge 4 lane-lists per xrow, write per-segment top-8 --------
  asm volatile("s_waitcnt vmcnt(0)" ::: "memory");
  __builtin_amdgcn_s_barrier();
  float* mv = (float*)smem;            // [256 xrows][4 lists][8] = 32KB
  int*   mi = (int*)(smem + 32768);
  #pragma unroll
  for (int fn = 0; fn < 2; ++fn) {
    const int xrL = wc * 64 + fn * 32 + l31;
    const int li  = wr * 2 + hi;
    #pragma unroll
    for (int q = 0; q < KSEL; ++q) {
      mv[xrL * 32 + li * 8 + q] = tv[fn][q];
      mi[xrL * 32 + li * 8 + q] = ti[fn][q];
    }
  }
  __syncthreads();
  if (t < 256) {
    float bvv[KSEL]; int bii[KSEL];
    #pragma unroll
    for (int q = 0; q < KSEL; ++q) { bvv[q] = -FLT_MAX; bii[q] = 0x7fffffff; }
    for (int c = 0; c < 32; ++c) {
      float cv = mv[t * 32 + c]; int ci = mi[t * 32 + c];
      if (cv > bvv[KSEL - 1] || (cv == bvv[KSEL - 1] && ci < bii[KSEL - 1])) {
        #pragma unroll
        for (int q = 0; q < KSEL; ++q) {
          if (cv > bvv[q] || (cv == bvv[q] && ci < bii[q])) {
            const float t0 = bvv[q]; bvv[q] = cv; cv = t0;
            const int   t1 = bii[q]; bii[q] = ci; ci = t1;
          }
        }
      }
    }
    const size_t base = ((size_t)(xbase + t) * NSPLIT + seg) * KSEL;
    #pragma unroll
    for (int q = 0; q < KSEL; ++q) { pval[base + q] = bvv[q]; pid[base + q] = bii[q]; }
  }
}

// ---------------------------------------------------------------------------
// Kernel 3: per row: merge 64 approx candidates -> top-24, exact f32 rescore
// of those 24, final top-8 (ties: lower id), gather + average.
// ---------------------------------------------------------------------------
__global__ __launch_bounds__(256)
void rescore_kernel(const float* __restrict__ X, const float* __restrict__ CB,
                    const float* __restrict__ c2g,
                    const float* __restrict__ pval, const int* __restrict__ pid,
                    float* __restrict__ out, float* __restrict__ out_ids, int nsplit) {
  const int row = blockIdx.x;
  const int t = threadIdx.x;
  __shared__ float xs[D_DIM];
  __shared__ int   scid[NC_RES];
  __shared__ float sv[NC_RES];
  __shared__ int   topid[KSEL];

  *(float4*)&xs[t * 4] = *(const float4*)(X + (size_t)row * D_DIM + t * 4);

  const int ncand = nsplit * KSEL;          // normally 64
  const int NC = NC_RES < ncand ? NC_RES : ncand;

  if (t < 64) {   // wave 0: merge candidates by approx score -> top-NC ids
    float v = -FLT_MAX; int idv = 0x7fffffff;
    if (t < ncand) {
      v   = pval[(size_t)row * ncand + t];
      idv = pid[(size_t)row * ncand + t];
    }
    for (int it = 0; it < NC; ++it) {
      float bv = v; int bid = idv;
      #pragma unroll
      for (int off = 32; off >= 1; off >>= 1) {
        float ov = __shfl_xor(bv, off, 64);
        int   oi = __shfl_xor(bid, off, 64);
        if (ov > bv || (ov == bv && oi < bid)) { bv = ov; bid = oi; }
      }
      if (t == 0) scid[it] = bid;
      if (idv == bid) v = -FLT_MAX;   // remove winner (ids unique)
    }
  }
  __syncthreads();

  const int w = t >> 6, ln = t & 63;
  for (int c = w; c < NC; c += 4) {
    const int id = scid[c];
    const float* cr = CB + (size_t)id * D_DIM;
    float s = 0.f;
    #pragma unroll
    for (int i = 0; i < 4; ++i) {
      const float4 cv = *(const float4*)(cr + ln * 4 + i * 256);
      const float4 xv = *(const float4*)&xs[ln * 4 + i * 256];
      s += cv.x * xv.x + cv.y * xv.y + cv.z * xv.z + cv.w * xv.w;
    }
    #pragma unroll
    for (int off = 32; off >= 1; off >>= 1) s += __shfl_xor(s, off, 64);
    if (ln == 0) sv[c] = 2.f * s - c2g[id];
  }
  __syncthreads();

  if (t == 0) {
    float bv[KSEL]; int bi[KSEL];
    #pragma unroll
    for (int q = 0; q < KSEL; ++q) { bv[q] = -FLT_MAX; bi[q] = 0x7fffffff; }
    for (int c = 0; c < NC; ++c) {
      float cv = sv[c]; int ci = scid[c];
      #pragma unroll
      for (int q = 0; q < KSEL; ++q) {
        if (cv > bv[q] || (cv == bv[q] && ci < bi[q])) {
          const float t0 = bv[q]; bv[q] = cv; cv = t0;
          const int   t1 = bi[q]; bi[q] = ci; ci = t1;
        }
      }
    }
    #pragma unroll
    for (int q = 0; q < KSEL; ++q) {
      topid[q] = bi[q];
      out_ids[(size_t)row * KSEL + q] = (float)bi[q];
    }
  }
  __syncthreads();

  float4 a = {0.f, 0.f, 0.f, 0.f};
  #pragma unroll
  for (int q = 0; q < KSEL; ++q) {
    const float4 cv = *(const float4*)(CB + (size_t)topid[q] * D_DIM + t * 4);
    a.x += cv.x; a.y += cv.y; a.z += cv.z; a.w += cv.w;
  }
  a.x *= 0.125f; a.y *= 0.125f; a.z *= 0.125f; a.w *= 0.125f;
  *(float4*)(out + (size_t)row * D_DIM + t * 4) = a;
}

// ---------------------------------------------------------------------------
extern "C" void kernel_launch(void* const* d_in, const int* in_sizes, int n_in,
                              void* d_out, int out_size, void* d_ws, size_t ws_size,
                              hipStream_t stream) {
  const float* X  = (const float*)d_in[0];
  const float* CB = (const float*)d_in[1];
  // d_in[2] = kcodes, fixed at 8 (compiled in)

  float* out     = (float*)d_out;
  float* out_ids = out + XN;

  const size_t XbB  = XN * 2;        // 16 MB
  const size_t CBbB = CBN * 2;       // 32 MB
  const size_t c2B  = C_TOTAL * 4;   // 64 KB
  const size_t pvB  = (size_t)R_TOTAL * NSPLIT * KSEL * 4;  // 2 MB

  char* p = (char*)d_ws;
  unsigned short* Xb;
  unsigned short* CBb;
  if (ws_size >= XbB + CBbB + c2B + 2 * pvB) {
    Xb  = (unsigned short*)p; p += XbB;
    CBb = (unsigned short*)p; p += CBbB;
  } else {
    // CB bf16 lives in d_out's outputs region (overwritten at the very end)
    CBb = (unsigned short*)d_out;
    Xb  = (unsigned short*)p; p += XbB;
  }
  float* c2   = (float*)p; p += c2B;
  float* pval = (float*)p; p += pvB;
  int*   pid  = (int*)p;

  hipLaunchKernelGGL(cvt_kernel, dim3((unsigned)((XN + CBN) / 8 / 256)), dim3(256), 0, stream,
                     X, CB, Xb, CBb);
  hipLaunchKernelGGL(c2_kernel, dim3(C_TOTAL / 4), dim3(256), 0, stream, CB, c2);
  hipLaunchKernelGGL(gemm_topk_kernel, dim3(32 * NSPLIT), dim3(512), 136 * 1024, stream,
                     Xb, CBb, c2, pval, pid);
  hipLaunchKernelGGL(rescore_kernel, dim3(R_TOTAL), dim3(256), 0, stream,
                     X, CB, c2, pval, pid, out, out_ids, NSPLIT);
}